// Round 10
// baseline (103.888 us; speedup 1.0000x reference)
//
#include <hip/hip_runtime.h>
#include <hip/hip_fp16.h>
#include <stdint.h>

typedef unsigned int  u32;
typedef unsigned short u16;

#define B_ROWS 131072
#define P_PRED 64
#define C_CLS  128
#define NPAIR  384               // C*L raw words for dtype detection
#define CAP    32                // max records per predicate (mean 6)
#define RPB    128               // rows per block (2 rows per thread)
#define TPB    512               // 8 waves; wave g owns predicates [8g, 8g+8)
#define GCAP   104               // record capacity per 8-pred group (mean 48)
#define LOG2E  1.4426950408889634f

#if __has_builtin(__builtin_amdgcn_exp2f)
#define EXP2F(x) __builtin_amdgcn_exp2f(x)
#else
#define EXP2F(x) exp2f(x)
#endif

#if __has_builtin(__builtin_amdgcn_rcpf)
#define RCPF(x) __builtin_amdgcn_rcpf(x)
#else
#define RCPF(x) (1.0f / (x))
#endif

__device__ __forceinline__ float bf16_to_f(u16 u) {
    return __uint_as_float(((u32)u) << 16);
}
__device__ __forceinline__ u16 f_to_bf16(float f) {
    u32 u = __float_as_uint(f);
    u += 0x7FFFu + ((u >> 16) & 1u);   // RNE
    return (u16)(u >> 16);
}
__device__ __forceinline__ u32 pack_bf16x2(float lo, float hi) {
    return (u32)f_to_bf16(lo) | ((u32)f_to_bf16(hi) << 16);
}
// fp16 pair helpers (u32 <-> __half2 bitcasts)
__device__ __forceinline__ u32 h2u(__half2 h) { union { __half2 h; u32 u; } v; v.h = h; return v.u; }
__device__ __forceinline__ __half2 u2h(u32 u) { union { __half2 h; u32 u; } v; v.u = u; return v.h; }
__device__ __forceinline__ u32 pack_f16x2(float lo, float hi) {
    return h2u(__floats2half2_rn(lo, hi));     // RN: 2x v_cvt_f16_f32 + pack
}

// ---------------------------------------------------------------------------
// R20: R19 (in-place R table, single-pass fp16, 4 blocks/CU) + SIGN-
// PARTITIONED record streams. R17/R19 both landed at the pessimistic edge
// of their prediction bands -> record loop is dependency-latency-bound:
// R-read -> cndmask(self) -> pk_mul -> pk_fma is a 4-deep chain per record.
// Fix via algebra: contribution = ssu * (R[c]*w), ssu chosen ONLY by record
// sign. Prep's CSR copy (same thread-per-pred step, zero new barriers)
// stores each pred's positive records first, then negatives; the loop
// accumulates TP / TN separately with body = srec b64 + R b32 + ONE
// v_pk_fma (accumulator chain broken by dual accumulators), and the self
// multiply moves to the f32 per-pred epilogue: acc = sp*TP + sn*TN.
// Slightly MORE precise than R19 (f32 self-multiply; smaller fp16
// accumulation magnitudes). Structure/LDS/barriers unchanged.
// Workspace d_ws: UNUSED.
// ---------------------------------------------------------------------------
__global__ __launch_bounds__(TPB, 8)
void ke_sgn(const u32* __restrict__ lidx_w,
            const u32* __restrict__ sb_w,
            const u32* __restrict__ w_w,
            const void* __restrict__ atoms_v,
            void* __restrict__ out_v) {
    __shared__ u32 S[8192];                   // 32 KB: prep scratch -> E2 -> R
    __shared__ uint2 srec[8 * GCAP];          // 6656 B (persists all phases)
    __shared__ unsigned char cnt8[P_PRED];    // 64 B total counts
    __shared__ unsigned char cnt8p[P_PRED];   // 64 B positive-prefix counts
    __shared__ u32 cslotS[C_CLS];             // 512 B clause slot triples

    const int tid = threadIdx.x;
    const int lane = tid & 63;
    const int g = __builtin_amdgcn_readfirstlane(tid >> 6);  // 0..7, SGPR
    const int rowBase = blockIdx.x * RPB;

    // ======== phase 0: inline prep (scratch aliased into S) ========
    int*   scnt  = (int*)&S[0];       // [64]
    int*   det   = (int*)&S[64];      // [3]
    int*   sidx  = (int*)&S[128];     // [384]
    int*   ssb   = (int*)&S[512];     // [384]
    u32*   recPk = &S[1024];          // [64][32]
    u32*   recWH = &S[3072];          // [64][32] pre-signed half2-dup weight

    if (tid < P_PRED) scnt[tid] = 0;
    if (tid < 3) det[tid] = 1;
    __syncthreads();
    if (tid < NPAIR / 2) {
        if (lidx_w[2 * tid + 1] != 0u) det[0] = 0;   // benign race (all write 0)
        if (sb_w[2 * tid + 1]   != 0u) det[1] = 0;
    }
    if (tid == 0 && (w_w[0] & 0xFFFFu) == 0u) det[2] = 0;
    __syncthreads();
    if (tid < NPAIR) {
        sidx[tid] = (int)(det[0] ? lidx_w[2 * tid] : lidx_w[tid]);
        ssb[tid]  = (int)(det[1] ? sb_w[2 * tid]   : sb_w[tid]);
    }
    __syncthreads();
    const bool bf16m = (det[2] != 0);            // latch before S is reused
    if (tid < NPAIR) {
        const int c = tid / 3;
        const int p = sidx[tid];
        const int slot = atomicAdd(&scnt[p], 1); // prep-only LDS atomics: fine
        float wraw = bf16m ? bf16_to_f((u16)(w_w[c / 2] >> ((c & 1) * 16)))
                           : __uint_as_float(w_w[c]);
        float wc = fminf(fmaxf(wraw, 0.0f), 500.0f);
        if (slot < CAP) {
            recPk[p * CAP + slot] = (u32)c << 8;          // R-table byte offset
            u32 wh2 = pack_f16x2(wc, wc);                 // duplicated half2
            if (!ssb[tid]) wh2 ^= 0x80008000u;            // pre-signed (sign bit
            recWH[p * CAP + slot] = wh2;                  //  also keys self-select)
        }
    }
    if (tid < C_CLS) {
        const int c = tid;
        const u32 s0 = 2u * (u32)sidx[3 * c]     + (ssb[3 * c]     ? 0u : 1u);
        const u32 s1 = 2u * (u32)sidx[3 * c + 1] + (ssb[3 * c + 1] ? 0u : 1u);
        const u32 s2 = 2u * (u32)sidx[3 * c + 2] + (ssb[3 * c + 2] ? 0u : 1u);
        cslotS[c] = s0 | (s1 << 8) | (s2 << 16);
    }
    __syncthreads();
    // CSR copy, SIGN-PARTITIONED: positives first, then negatives
    if (tid < P_PRED) {
        const int p = tid;
        const int gg = p >> 3;
        const int n = min(scnt[p], CAP);
        int off = 0;
        for (int pb = gg * 8; pb < p; ++pb) off += min(scnt[pb], CAP);
        int ncl = 0;
        for (int j = 0; j < n; ++j) {                      // pass 1: w >= 0
            const u32 wv = recWH[p * CAP + j];
            if (!(wv & 0x80000000u) && off + ncl < GCAP) {
                srec[gg * GCAP + off + ncl] = make_uint2(recPk[p * CAP + j], wv);
                ++ncl;
            }
        }
        const int npos = ncl;
        for (int j = 0; j < n; ++j) {                      // pass 2: w < 0
            const u32 wv = recWH[p * CAP + j];
            if ((wv & 0x80000000u) && off + ncl < GCAP) {
                srec[gg * GCAP + off + ncl] = make_uint2(recPk[p * CAP + j], wv);
                ++ncl;
            }
        }
        cnt8[p]  = (unsigned char)ncl;
        cnt8p[p] = (unsigned char)npos;
    }
    __syncthreads();   // srec/cnt8 ready; prep scratch in S now dead

    // ======== phase 1: stage E2 as half2 (paired-row b32 writes) ========
    {
        const int a = tid & 63;                  // row pair (2a, 2a+1)
        const int c0 = (tid >> 6) * 8;           // 8-atom chunk
        if (bf16m) {
            const u16* gp0 = (const u16*)atoms_v + (size_t)(rowBase + 2 * a) * P_PRED + c0;
            uint4 v0 = *(const uint4*)gp0;            // row 2a
            uint4 v1 = *(const uint4*)(gp0 + P_PRED); // row 2a+1
            u32 w0[4] = {v0.x, v0.y, v0.z, v0.w};
            u32 w1[4] = {v1.x, v1.y, v1.z, v1.w};
#pragma unroll
            for (int k = 0; k < 4; ++k) {
                float xl0 = __uint_as_float(w0[k] << 16) * LOG2E;
                float xh0 = __uint_as_float(w0[k] & 0xFFFF0000u) * LOG2E;
                float xl1 = __uint_as_float(w1[k] << 16) * LOG2E;
                float xh1 = __uint_as_float(w1[k] & 0xFFFF0000u) * LOG2E;
                float el0 = EXP2F(xl0), eh0 = EXP2F(xh0);
                float el1 = EXP2F(xl1), eh1 = EXP2F(xh1);
                const int m = c0 + 2 * k;
                S[(2 * m)     * 64 + a] = pack_f16x2(el0, el1);
                S[(2 * m + 1) * 64 + a] = pack_f16x2(RCPF(el0), RCPF(el1));
                S[(2 * m + 2) * 64 + a] = pack_f16x2(eh0, eh1);
                S[(2 * m + 3) * 64 + a] = pack_f16x2(RCPF(eh0), RCPF(eh1));
            }
        } else {
            const float* gp0 = (const float*)atoms_v + (size_t)(rowBase + 2 * a) * P_PRED + c0;
            float4 u0 = *(const float4*)gp0;
            float4 u1 = *(const float4*)(gp0 + 4);
            float4 d0 = *(const float4*)(gp0 + P_PRED);
            float4 d1 = *(const float4*)(gp0 + P_PRED + 4);
            float r0[8] = {u0.x, u0.y, u0.z, u0.w, u1.x, u1.y, u1.z, u1.w};
            float r1[8] = {d0.x, d0.y, d0.z, d0.w, d1.x, d1.y, d1.z, d1.w};
#pragma unroll
            for (int k = 0; k < 8; ++k) {
                float e0 = EXP2F(r0[k] * LOG2E);
                float e1 = EXP2F(r1[k] * LOG2E);
                const int m = c0 + k;
                S[(2 * m)     * 64 + a] = pack_f16x2(e0, e1);
                S[(2 * m + 1) * 64 + a] = pack_f16x2(RCPF(e0), RCPF(e1));
            }
        }
    }
    __syncthreads();

    // ======== phase 1b: self preload + in-place R table ========
    u32 selfP[8], selfN[8];
#pragma unroll
    for (int pp = 0; pp < 8; ++pp) {
        selfP[pp] = S[(16 * g + 2 * pp)     * 64 + lane];
        selfN[pp] = S[(16 * g + 2 * pp + 1) * 64 + lane];
    }
    u32 rt[16];
#pragma unroll
    for (int k = 0; k < 16; ++k) {
        const int c  = g * 16 + k;                 // wave-uniform clause
        const u32 cs = cslotS[c];                  // broadcast LDS read
        const u32 e0 = S[((cs      ) & 255u) * 64 + lane];
        const u32 e1 = S[((cs >>  8) & 255u) * 64 + lane];
        const u32 e2 = S[((cs >> 16) & 255u) * 64 + lane];
        const __half2 D = __hadd2(u2h(e0), __hadd2(u2h(e1), u2h(e2)));
        rt[k] = h2u(h2rcp(D));
    }
    __syncthreads();       // ALL E2 reads complete (incl. other waves')
#pragma unroll
    for (int k = 0; k < 16; ++k) S[(g * 16 + k) * 64 + lane] = rt[k];
    __syncthreads();       // R table ready

    // ======== phase 2: record loop (sign-partitioned, 1 fma/record) ======
    const int q2 = 2 * lane;                     // u16 row index of this row pair
    const char* Rc = (const char*)S + lane * 4;  // per-lane R base (byte)
    float2 acc[8];
    int j = g * GCAP;                            // stream cursor

#pragma unroll
    for (int pp = 0; pp < 8; ++pp) {
        const int nT = (int)cnt8[pp + g * 8];
        const int nP = (int)cnt8p[pp + g * 8];
        __half2 aP0 = u2h(0u), aP1 = u2h(0u);
        __half2 aN0 = u2h(0u), aN1 = u2h(0u);

#define REC_BODY(J, A)                                                        \
        {                                                                     \
            const uint2 rec = srec[J];                 /* b64 broadcast */    \
            const u32 Rv  = *(const u32*)(Rc + (rec.x & 0x7F00u));            \
            A = __hfma2(u2h(Rv), u2h(rec.y), A);       /* one fma, no sel */  \
        }

        int e = 0;
        for (; e + 3 < nP; e += 4) {       // positive run, unroll x4
            REC_BODY(j,     aP0)
            REC_BODY(j + 1, aP1)
            REC_BODY(j + 2, aP0)
            REC_BODY(j + 3, aP1)
            j += 4;
        }
        for (; e < nP; ++e, ++j) REC_BODY(j, aP0)
        for (; e + 3 < nT; e += 4) {       // negative run, unroll x4
            REC_BODY(j,     aN0)
            REC_BODY(j + 1, aN1)
            REC_BODY(j + 2, aN0)
            REC_BODY(j + 3, aN1)
            j += 4;
        }
        for (; e < nT; ++e, ++j) REC_BODY(j, aN0)
#undef REC_BODY

        // per-pred f32 epilogue: acc = sp*TP + sn*TN  (self applied ONCE)
        const __half2 TP = __hadd2(aP0, aP1);
        const __half2 TN = __hadd2(aN0, aN1);
        const __half2 hp = u2h(selfP[pp]);
        const __half2 hn = u2h(selfN[pp]);
        acc[pp] = make_float2(
            fmaf(__low2float(hp),  __low2float(TP),
                 __low2float(hn)  * __low2float(TN)),
            fmaf(__high2float(hp), __high2float(TP),
                 __high2float(hn) * __high2float(TN)));
    }

    // ======== phase 3: direct stores (R9 epilogue) ========
    if (bf16m) {
        u16* op0 = (u16*)out_v + (size_t)(rowBase + q2) * P_PRED + g * 8;
        u16* op1 = op0 + P_PRED;
        uint4 o0, o1v;
        o0.x  = pack_bf16x2(acc[0].x, acc[1].x);
        o0.y  = pack_bf16x2(acc[2].x, acc[3].x);
        o0.z  = pack_bf16x2(acc[4].x, acc[5].x);
        o0.w  = pack_bf16x2(acc[6].x, acc[7].x);
        o1v.x = pack_bf16x2(acc[0].y, acc[1].y);
        o1v.y = pack_bf16x2(acc[2].y, acc[3].y);
        o1v.z = pack_bf16x2(acc[4].y, acc[5].y);
        o1v.w = pack_bf16x2(acc[6].y, acc[7].y);
        *(uint4*)op0 = o0;
        *(uint4*)op1 = o1v;
    } else {
        float* op0 = (float*)out_v + (size_t)(rowBase + q2) * P_PRED + g * 8;
        float* op1 = op0 + P_PRED;
        *(float4*)(op0)     = make_float4(acc[0].x, acc[1].x, acc[2].x, acc[3].x);
        *(float4*)(op0 + 4) = make_float4(acc[4].x, acc[5].x, acc[6].x, acc[7].x);
        *(float4*)(op1)     = make_float4(acc[0].y, acc[1].y, acc[2].y, acc[3].y);
        *(float4*)(op1 + 4) = make_float4(acc[4].y, acc[5].y, acc[6].y, acc[7].y);
    }
}

extern "C" void kernel_launch(void* const* d_in, const int* in_sizes, int n_in,
                              void* d_out, int out_size, void* d_ws, size_t ws_size,
                              hipStream_t stream_h) {
    const u32* clause_weights = (const u32*)d_in[1]; // bf16 or f32 [128]
    const u32* literal_idx    = (const u32*)d_in[2]; // int32 or int64 [128,3]
    const u32* sign_bits      = (const u32*)d_in[3]; // int32 or int64 [128,3]
    (void)d_ws; (void)ws_size;                       // workspace unused

    ke_sgn<<<B_ROWS / RPB, TPB, 0, stream_h>>>(literal_idx, sign_bits,
                                               clause_weights, d_in[0],
                                               d_out);
}

// Round 13
// 97.065 us; speedup vs baseline: 1.0703x; 1.0703x over previous
//
#include <hip/hip_runtime.h>
#include <hip/hip_fp16.h>
#include <stdint.h>

typedef unsigned int  u32;
typedef unsigned short u16;

#define B_ROWS 131072
#define P_PRED 64
#define C_CLS  128
#define NPAIR  384               // C*L raw words for dtype detection
#define CAP    32                // max records per predicate (mean 6)
#define RPB    128               // rows per block (2 rows per thread)
#define TPB    512               // 8 waves; wave g owns predicates [8g, 8g+8)
#define GCAP   104               // record capacity per 8-pred group (mean 48)
#define LOG2E  1.4426950408889634f

#if __has_builtin(__builtin_amdgcn_exp2f)
#define EXP2F(x) __builtin_amdgcn_exp2f(x)
#else
#define EXP2F(x) exp2f(x)
#endif

#if __has_builtin(__builtin_amdgcn_rcpf)
#define RCPF(x) __builtin_amdgcn_rcpf(x)
#else
#define RCPF(x) (1.0f / (x))
#endif

__device__ __forceinline__ float bf16_to_f(u16 u) {
    return __uint_as_float(((u32)u) << 16);
}
__device__ __forceinline__ u16 f_to_bf16(float f) {
    u32 u = __float_as_uint(f);
    u += 0x7FFFu + ((u >> 16) & 1u);   // RNE
    return (u16)(u >> 16);
}
__device__ __forceinline__ u32 pack_bf16x2(float lo, float hi) {
    return (u32)f_to_bf16(lo) | ((u32)f_to_bf16(hi) << 16);
}
// fp16 pair helpers (u32 <-> __half2 bitcasts)
__device__ __forceinline__ u32 h2u(__half2 h) { union { __half2 h; u32 u; } v; v.h = h; return v.u; }
__device__ __forceinline__ __half2 u2h(u32 u) { union { __half2 h; u32 u; } v; v.u = u; return v.h; }
__device__ __forceinline__ u32 pack_f16x2(float lo, float hi) {
    return h2u(__floats2half2_rn(lo, hi));     // RN: 2x v_cvt_f16_f32 + pack
}

// ---------------------------------------------------------------------------
// R23 = R22 RESUBMIT ("MI355X container failed twice" — infrastructure, no
// kernel signal; same as R8 which ran clean on resubmit. Code re-audited:
// cursor algebra consistent writer/reader at padded counts, pads zeroed and
// exactly-neutral via fma, 16B alignment of all uint4 reads, no OOB.)
//
// R22 = R21 with the stream-cursor BUG fixed (one line). R21's absmax-85
// failure: the reader's pair loop advances j by 2*npair = padded count
// ALREADY (the last pair consumes the pad slot when n is odd); the extra
// `j += (n & 1)` double-counted the pad and shifted every subsequent
// stream by one slot. Deleted. Everything else identical to R21:
//   R19 base (in-place R table, single-pass fp16, 4 blocks/CU, 98.08us) +
//   1. even-aligned padded streams -> TWO records per ds_read_b128
//      (DS 2 -> 1.5 ops/record, half the loop iterations, two independent
//      record bodies straight-line per iteration). Pad records {pk=0,w=+0}
//      contribute exactly +-0 via fma.
//   2. A = fma(Rv, ssu*w, A): select+mul overlap the R-read latency;
//      post-R-read chain = ONE fma.
// Workspace d_ws: UNUSED.
// ---------------------------------------------------------------------------
__global__ __launch_bounds__(TPB, 8)
void ke_pair2(const u32* __restrict__ lidx_w,
              const u32* __restrict__ sb_w,
              const u32* __restrict__ w_w,
              const void* __restrict__ atoms_v,
              void* __restrict__ out_v) {
    __shared__ u32 S[8192];                          // 32 KB: scratch -> E2 -> R
    __shared__ __align__(16) uint2 srec[8 * GCAP];   // 6656 B (persists)
    __shared__ unsigned char cnt8[P_PRED];           // 64 B stored counts
    __shared__ u32 cslotS[C_CLS];                    // 512 B clause slot triples

    const int tid = threadIdx.x;
    const int lane = tid & 63;
    const int g = __builtin_amdgcn_readfirstlane(tid >> 6);  // 0..7, SGPR
    const int rowBase = blockIdx.x * RPB;

    // ======== phase 0: inline prep (scratch aliased into S) ========
    int*   scnt  = (int*)&S[0];       // [64]
    int*   det   = (int*)&S[64];      // [3]
    int*   sidx  = (int*)&S[128];     // [384]
    int*   ssb   = (int*)&S[512];     // [384]
    u32*   recPk = &S[1024];          // [64][32]
    u32*   recWH = &S[3072];          // [64][32] pre-signed half2-dup weight

    if (tid < P_PRED) scnt[tid] = 0;
    if (tid < 3) det[tid] = 1;
    // zero srec so inter-stream pad slots are harmless (w=+0 records)
    srec[tid] = make_uint2(0u, 0u);
    if (tid < 8 * GCAP - TPB) srec[TPB + tid] = make_uint2(0u, 0u);
    __syncthreads();
    if (tid < NPAIR / 2) {
        if (lidx_w[2 * tid + 1] != 0u) det[0] = 0;   // benign race (all write 0)
        if (sb_w[2 * tid + 1]   != 0u) det[1] = 0;
    }
    if (tid == 0 && (w_w[0] & 0xFFFFu) == 0u) det[2] = 0;
    __syncthreads();
    if (tid < NPAIR) {
        sidx[tid] = (int)(det[0] ? lidx_w[2 * tid] : lidx_w[tid]);
        ssb[tid]  = (int)(det[1] ? sb_w[2 * tid]   : sb_w[tid]);
    }
    __syncthreads();
    const bool bf16m = (det[2] != 0);            // latch before S is reused
    if (tid < NPAIR) {
        const int c = tid / 3;
        const int p = sidx[tid];
        const int slot = atomicAdd(&scnt[p], 1); // prep-only LDS atomics: fine
        float wraw = bf16m ? bf16_to_f((u16)(w_w[c / 2] >> ((c & 1) * 16)))
                           : __uint_as_float(w_w[c]);
        float wc = fminf(fmaxf(wraw, 0.0f), 500.0f);
        if (slot < CAP) {
            recPk[p * CAP + slot] = (u32)c << 8;          // R-table byte offset
            u32 wh2 = pack_f16x2(wc, wc);                 // duplicated half2
            if (!ssb[tid]) wh2 ^= 0x80008000u;            // pre-signed (sign bit
            recWH[p * CAP + slot] = wh2;                  //  also keys self-select)
        }
    }
    if (tid < C_CLS) {
        const int c = tid;
        const u32 s0 = 2u * (u32)sidx[3 * c]     + (ssb[3 * c]     ? 0u : 1u);
        const u32 s1 = 2u * (u32)sidx[3 * c + 1] + (ssb[3 * c + 1] ? 0u : 1u);
        const u32 s2 = 2u * (u32)sidx[3 * c + 2] + (ssb[3 * c + 2] ? 0u : 1u);
        cslotS[c] = s0 | (s1 << 8) | (s2 << 16);
    }
    __syncthreads();
    // CSR copy with EVEN-ALIGNED stream starts (pads stay zero)
    if (tid < P_PRED) {
        const int p = tid;
        const int gg = p >> 3;
        const int n = min(scnt[p], CAP);
        int off = 0;
        for (int pb = gg * 8; pb < p; ++pb)
            off += (min(scnt[pb], CAP) + 1) & ~1;        // padded counts
        int ncl = 0;
        for (int j = 0; j < n; ++j) {
            if (off + j < GCAP) {
                srec[gg * GCAP + off + j] =
                    make_uint2(recPk[p * CAP + j], recWH[p * CAP + j]);
                ++ncl;
            }
        }
        if ((ncl & 1) && off + ncl >= GCAP) --ncl;       // keep pad slot in-group
        cnt8[p] = (unsigned char)ncl;
    }
    __syncthreads();   // srec/cnt8 ready; prep scratch in S now dead

    // ======== phase 1: stage E2 as half2 (paired-row b32 writes) ========
    {
        const int a = tid & 63;                  // row pair (2a, 2a+1)
        const int c0 = (tid >> 6) * 8;           // 8-atom chunk
        if (bf16m) {
            const u16* gp0 = (const u16*)atoms_v + (size_t)(rowBase + 2 * a) * P_PRED + c0;
            uint4 v0 = *(const uint4*)gp0;            // row 2a
            uint4 v1 = *(const uint4*)(gp0 + P_PRED); // row 2a+1
            u32 w0[4] = {v0.x, v0.y, v0.z, v0.w};
            u32 w1[4] = {v1.x, v1.y, v1.z, v1.w};
#pragma unroll
            for (int k = 0; k < 4; ++k) {
                float xl0 = __uint_as_float(w0[k] << 16) * LOG2E;
                float xh0 = __uint_as_float(w0[k] & 0xFFFF0000u) * LOG2E;
                float xl1 = __uint_as_float(w1[k] << 16) * LOG2E;
                float xh1 = __uint_as_float(w1[k] & 0xFFFF0000u) * LOG2E;
                float el0 = EXP2F(xl0), eh0 = EXP2F(xh0);
                float el1 = EXP2F(xl1), eh1 = EXP2F(xh1);
                const int m = c0 + 2 * k;
                S[(2 * m)     * 64 + a] = pack_f16x2(el0, el1);
                S[(2 * m + 1) * 64 + a] = pack_f16x2(RCPF(el0), RCPF(el1));
                S[(2 * m + 2) * 64 + a] = pack_f16x2(eh0, eh1);
                S[(2 * m + 3) * 64 + a] = pack_f16x2(RCPF(eh0), RCPF(eh1));
            }
        } else {
            const float* gp0 = (const float*)atoms_v + (size_t)(rowBase + 2 * a) * P_PRED + c0;
            float4 u0 = *(const float4*)gp0;
            float4 u1 = *(const float4*)(gp0 + 4);
            float4 d0 = *(const float4*)(gp0 + P_PRED);
            float4 d1 = *(const float4*)(gp0 + P_PRED + 4);
            float r0[8] = {u0.x, u0.y, u0.z, u0.w, u1.x, u1.y, u1.z, u1.w};
            float r1[8] = {d0.x, d0.y, d0.z, d0.w, d1.x, d1.y, d1.z, d1.w};
#pragma unroll
            for (int k = 0; k < 8; ++k) {
                float e0 = EXP2F(r0[k] * LOG2E);
                float e1 = EXP2F(r1[k] * LOG2E);
                const int m = c0 + k;
                S[(2 * m)     * 64 + a] = pack_f16x2(e0, e1);
                S[(2 * m + 1) * 64 + a] = pack_f16x2(RCPF(e0), RCPF(e1));
            }
        }
    }
    __syncthreads();

    // ======== phase 1b: self preload + in-place R table ========
    u32 selfP[8], selfN[8];
#pragma unroll
    for (int pp = 0; pp < 8; ++pp) {
        selfP[pp] = S[(16 * g + 2 * pp)     * 64 + lane];
        selfN[pp] = S[(16 * g + 2 * pp + 1) * 64 + lane];
    }
    u32 rt[16];
#pragma unroll
    for (int k = 0; k < 16; ++k) {
        const int c  = g * 16 + k;                 // wave-uniform clause
        const u32 cs = cslotS[c];                  // broadcast LDS read
        const u32 e0 = S[((cs      ) & 255u) * 64 + lane];
        const u32 e1 = S[((cs >>  8) & 255u) * 64 + lane];
        const u32 e2 = S[((cs >> 16) & 255u) * 64 + lane];
        const __half2 D = __hadd2(u2h(e0), __hadd2(u2h(e1), u2h(e2)));
        rt[k] = h2u(h2rcp(D));
    }
    __syncthreads();       // ALL E2 reads complete (incl. other waves')
#pragma unroll
    for (int k = 0; k < 16; ++k) S[(g * 16 + k) * 64 + lane] = rt[k];
    __syncthreads();       // R table ready

    // ======== phase 2: record loop (b128 pairs, 1 fma post-load) ========
    const int q2 = 2 * lane;                     // u16 row index of this row pair
    const char* Rc = (const char*)S + lane * 4;  // per-lane R base (byte)
    float2 acc[8];
    int j = g * GCAP;                            // stream cursor (even starts)

#pragma unroll
    for (int pp = 0; pp < 8; ++pp) {
        const int n = (int)cnt8[pp + g * 8];
        const int npair = (n + 1) >> 1;          // pad slot is zero -> harmless
        const u32 sp = selfP[pp], sn = selfN[pp];
        __half2 a0 = u2h(0u), a1 = u2h(0u);
        __half2 a2 = u2h(0u), a3 = u2h(0u);

#define PAIR_BODY(J, A, B)                                                    \
        {                                                                     \
            const uint4 q = *(const uint4*)&srec[J];   /* 2 records, b128 */  \
            const u32 R0 = *(const u32*)(Rc + (q.x & 0x7F00u));               \
            const u32 R1 = *(const u32*)(Rc + (q.z & 0x7F00u));               \
            const u32 s0 = ((int)q.y < 0) ? sn : sp;                          \
            const u32 s1 = ((int)q.w < 0) ? sn : sp;                          \
            const __half2 m0 = __hmul2(u2h(s0), u2h(q.y));  /* pre-R-load */  \
            const __half2 m1 = __hmul2(u2h(s1), u2h(q.w));                    \
            A = __hfma2(u2h(R0), m0, A);               /* 1 fma post-load */  \
            B = __hfma2(u2h(R1), m1, B);                                      \
        }

        int k = 0;
        for (; k + 1 < npair; k += 2, j += 4) {  // 2 pairs (4 records) / iter
            PAIR_BODY(j,     a0, a1)
            PAIR_BODY(j + 2, a2, a3)
        }
        for (; k < npair; ++k, j += 2) PAIR_BODY(j, a0, a1)
#undef PAIR_BODY
        // NOTE: j has advanced 2*npair = (n+1)&~1 slots — the padded count.
        // (R21's extra `j += (n & 1)` here double-counted the pad: BUG.)

        const __half2 at = __hadd2(__hadd2(a0, a1), __hadd2(a2, a3));
        acc[pp] = make_float2(__low2float(at), __high2float(at));
    }

    // ======== phase 3: direct stores (R9 epilogue) ========
    if (bf16m) {
        u16* op0 = (u16*)out_v + (size_t)(rowBase + q2) * P_PRED + g * 8;
        u16* op1 = op0 + P_PRED;
        uint4 o0, o1v;
        o0.x  = pack_bf16x2(acc[0].x, acc[1].x);
        o0.y  = pack_bf16x2(acc[2].x, acc[3].x);
        o0.z  = pack_bf16x2(acc[4].x, acc[5].x);
        o0.w  = pack_bf16x2(acc[6].x, acc[7].x);
        o1v.x = pack_bf16x2(acc[0].y, acc[1].y);
        o1v.y = pack_bf16x2(acc[2].y, acc[3].y);
        o1v.z = pack_bf16x2(acc[4].y, acc[5].y);
        o1v.w = pack_bf16x2(acc[6].y, acc[7].y);
        *(uint4*)op0 = o0;
        *(uint4*)op1 = o1v;
    } else {
        float* op0 = (float*)out_v + (size_t)(rowBase + q2) * P_PRED + g * 8;
        float* op1 = op0 + P_PRED;
        *(float4*)(op0)     = make_float4(acc[0].x, acc[1].x, acc[2].x, acc[3].x);
        *(float4*)(op0 + 4) = make_float4(acc[4].x, acc[5].x, acc[6].x, acc[7].x);
        *(float4*)(op1)     = make_float4(acc[0].y, acc[1].y, acc[2].y, acc[3].y);
        *(float4*)(op1 + 4) = make_float4(acc[4].y, acc[5].y, acc[6].y, acc[7].y);
    }
}

extern "C" void kernel_launch(void* const* d_in, const int* in_sizes, int n_in,
                              void* d_out, int out_size, void* d_ws, size_t ws_size,
                              hipStream_t stream_h) {
    const u32* clause_weights = (const u32*)d_in[1]; // bf16 or f32 [128]
    const u32* literal_idx    = (const u32*)d_in[2]; // int32 or int64 [128,3]
    const u32* sign_bits      = (const u32*)d_in[3]; // int32 or int64 [128,3]
    (void)d_ws; (void)ws_size;                       // workspace unused

    ke_pair2<<<B_ROWS / RPB, TPB, 0, stream_h>>>(literal_idx, sign_bits,
                                                 clause_weights, d_in[0],
                                                 d_out);
}